// Round 6
// baseline (381.936 us; speedup 1.0000x reference)
//
#include <hip/hip_runtime.h>
#include <stdint.h>

// ---- problem constants ----
#define DIMX 1024
#define DIM_INNER 2048
#define BATCH 4
#define SEQ 4096
#define M_TOTAL (BATCH * SEQ)   // 16384
#define N_HG (2 * DIM_INNER)    // 4096
#define NCHUNK 32               // chunks along S
#define CLEN 128                // steps per chunk

typedef unsigned short u16;
typedef __attribute__((ext_vector_type(8))) short short8;   // 8 x bf16 MFMA frag
typedef __attribute__((ext_vector_type(4))) float floatx4;  // MFMA acc
typedef __attribute__((ext_vector_type(2))) unsigned int u32x2;  // clang-native (nt builtins)

// ---- bf16 helpers (bit-level, RNE) ----
__device__ __forceinline__ float bflo(uint32_t u) { return __uint_as_float(u << 16); }
__device__ __forceinline__ float bfhi(uint32_t u) { return __uint_as_float(u & 0xffff0000u); }
__device__ __forceinline__ uint32_t f2bf_bits(float f) {
    uint32_t u = __float_as_uint(f);
    return (u + 0x7fffu + ((u >> 16) & 1u)) >> 16;  // round-to-nearest-even
}

#define GCAST(p) (const __attribute__((address_space(1))) uint32_t*)(const void*)(p)
#define LCAST(p) (__attribute__((address_space(3))) uint32_t*)(void*)(p)
// raw barrier + IR-level fence (plain LDS loads may not cross)
#define BAR()                                          \
    do {                                               \
        __builtin_amdgcn_s_barrier();                  \
        asm volatile("" ::: "memory");                 \
    } while (0)
// drain this wave's ds_reads before the phase's MFMA + pin scheduling (rule #18)
#define LGKM0()                                                  \
    do {                                                         \
        asm volatile("s_waitcnt lgkmcnt(0)" ::: "memory");       \
        __builtin_amdgcn_sched_barrier(0);                       \
    } while (0)
#define VMCNT_(n) asm volatile("s_waitcnt vmcnt(" #n ")" ::: "memory")
#define VMCNT(n) VMCNT_(n)

// ============================================================
// prep kernel: fuses x-cast + Whg transpose + Wout transpose. (unchanged)
// ============================================================
__global__ __launch_bounds__(256) void prep(const float* __restrict__ x,
                                            const float* __restrict__ Whg,
                                            const float* __restrict__ Wout,
                                            u16* __restrict__ xb,
                                            u16* __restrict__ whgt,
                                            u16* __restrict__ woutt) {
    __shared__ float tile[64][65];
    const int bid = blockIdx.x;
    const int tid = threadIdx.x;
    if (bid < 2048) {
        const int n4 = M_TOTAL * DIMX / 4;
        const float4* in4 = (const float4*)x;
        ushort4* out4 = (ushort4*)xb;
        for (int i = bid * 256 + tid; i < n4; i += 2048 * 256) {
            float4 v = in4[i];
            ushort4 o;
            o.x = (u16)f2bf_bits(v.x);
            o.y = (u16)f2bf_bits(v.y);
            o.z = (u16)f2bf_bits(v.z);
            o.w = (u16)f2bf_bits(v.w);
            out4[i] = o;
        }
        return;
    }
    const float* in;
    u16* out;
    int R, C, tb;
    if (bid < 3072) {
        in = Whg; out = whgt; R = DIMX; C = N_HG; tb = bid - 2048;
    } else {
        in = Wout; out = woutt; R = DIM_INNER; C = DIMX; tb = bid - 3072;
    }
    const int tilesx = C / 64;
    const int c0 = (tb % tilesx) * 64, r0 = (tb / tilesx) * 64;
    const int tx = tid & 63, ty = tid >> 6;  // 64 x 4
#pragma unroll
    for (int i = ty; i < 64; i += 4)
        tile[i][tx] = in[(size_t)(r0 + i) * C + c0 + tx];
    __syncthreads();
#pragma unroll
    for (int i = ty; i < 64; i += 4)
        out[(size_t)(c0 + i) * R + r0 + tx] = (u16)f2bf_bits(tile[tx][i]);
}

// ============================================================
// GEMM1 fused (R15 = R14, compile-fixed).
// 8-phase 256-wide template (T2+T3+T4+T5) + XCD remap (T1) + nt av stores.
// av is a write-once stream (134 MB) -> nt stores kill the L2
// read-for-ownership (~105 MB of the 147.6 MB FETCH_SIZE) and shorten
// the per-generation store-drain tail. grid 1024 blocks (1D).
// ============================================================
__global__ __launch_bounds__(512, 2) void gemm1_k(const u16* __restrict__ A,
                                                  const u16* __restrict__ Bt,
                                                  uint32_t* __restrict__ av,
                                                  float2* __restrict__ sumAV) {
    __shared__ alignas(16) u16 smem16[65536];  // 128 KB
    const int tid = threadIdx.x;
    const int lane = tid & 63;
    const int w = tid >> 6;
    const int wr = w >> 2;
    const int wc = w & 3;
    // T1 XCD-aware bijective remap (1024 blocks, 8 XCDs)
    const int wgid = blockIdx.x;
    const int xcd = wgid & 7;
    const int idx = wgid >> 3;          // 0..127
    const int xt = idx & 15;            // column tile 0..15
    const int yt = (idx >> 4) * 8 + xcd; // row tile 0..63, yt%8 == xcd
    const size_t m0 = (size_t)yt * 256;
    const int n0 = xt * 128;
#define X1 0
#define Y1 32768

    floatx4 acch[8][2], accg[8][2];
#pragma unroll
    for (int i = 0; i < 8; ++i)
#pragma unroll
        for (int j = 0; j < 2; ++j) {
            acch[i][j] = (floatx4){0.f, 0.f, 0.f, 0.f};
            accg[i][j] = (floatx4){0.f, 0.f, 0.f, 0.f};
        }

    // fragment addressing (u16 indices); row stride 64 u16, slot = 8 u16 (16B)
    const int fr = lane & 15;
    const int kb = lane >> 4;
    const int sw0 = kb ^ (fr & 7);                       // swizzled slot, kstep 0
    const int a0 = (wr * 128 + fr) * 64 + sw0 * 8;       // kstep1 = a0 ^ 32
    const int a1 = a0 ^ 32;
    const int b0 = 16384 + (wc * 32 + fr) * 64 + sw0 * 8;
    const int b1 = b0 ^ 32;

    // staging: lane covers (row = 8w + lane>>3, slot' = lane&7); global slot
    // = slot' ^ (row&7) = (lane&7)^(lane>>3). LDS dest stays linear.
    const int sr = lane >> 3;
    const int sswz = (lane & 7) ^ sr;
    const u16* pA = A + (m0 + w * 8 + sr) * DIMX + sswz * 8;
    const u16* pBh = Bt + ((size_t)(n0 + w * 8 + sr)) * DIMX + sswz * 8;
    const u16* pBg = pBh + (size_t)DIM_INNER * DIMX;

#define ST1A(bufb, kt, h, l)                                                        \
    __builtin_amdgcn_global_load_lds(                                               \
        GCAST(pA + (size_t)((h) * 128 + (l) * 64) * DIMX + (kt) * 64),              \
        LCAST(smem16 + (bufb) + (h) * 8192 + (l) * 4096 + w * 512), 16, 0, 0)
#define ST1H(bufb, kt, l)                                                           \
    __builtin_amdgcn_global_load_lds(                                               \
        GCAST(pBh + (size_t)((l) * 64) * DIMX + (kt) * 64),                         \
        LCAST(smem16 + (bufb) + 16384 + (l) * 4096 + w * 512), 16, 0, 0)
#define ST1G(bufb, kt, l)                                                           \
    __builtin_amdgcn_global_load_lds(                                               \
        GCAST(pBg + (size_t)((l) * 64) * DIMX + (kt) * 64),                         \
        LCAST(smem16 + (bufb) + 24576 + (l) * 4096 + w * 512), 16, 0, 0)

#define LDS8(idx) (*(const short8*)(smem16 + (idx)))
    short8 af[2][4], bh[2][2], bg[2][2];
#define RDA1(bufb, mh)                                                  \
    do {                                                                \
        _Pragma("unroll") for (int i_ = 0; i_ < 4; ++i_) {              \
            af[0][i_] = LDS8((bufb) + a0 + ((mh) * 4 + i_) * 1024);     \
            af[1][i_] = LDS8((bufb) + a1 + ((mh) * 4 + i_) * 1024);     \
        }                                                               \
    } while (0)
#define RDBH1(bufb)                                                     \
    do {                                                                \
        _Pragma("unroll") for (int j_ = 0; j_ < 2; ++j_) {              \
            bh[0][j_] = LDS8((bufb) + b0 + j_ * 1024);                  \
            bh[1][j_] = LDS8((bufb) + b1 + j_ * 1024);                  \
        }                                                               \
    } while (0)
#define RDBG1(bufb)                                                     \
    do {                                                                \
        _Pragma("unroll") for (int j_ = 0; j_ < 2; ++j_) {              \
            bg[0][j_] = LDS8((bufb) + b0 + 8192 + j_ * 1024);           \
            bg[1][j_] = LDS8((bufb) + b1 + 8192 + j_ * 1024);           \
        }                                                               \
    } while (0)
#define MM1(ACC, IB, BF)                                                                     \
    do {                                                                                     \
        __builtin_amdgcn_s_setprio(1);                                                       \
        _Pragma("unroll") for (int i_ = 0; i_ < 4; ++i_)                                     \
            _Pragma("unroll") for (int j_ = 0; j_ < 2; ++j_) {                               \
            ACC[(IB) + i_][j_] = __builtin_amdgcn_mfma_f32_16x16x32_bf16(                    \
                af[0][i_], BF[0][j_], ACC[(IB) + i_][j_], 0, 0, 0);                          \
            ACC[(IB) + i_][j_] = __builtin_amdgcn_mfma_f32_16x16x32_bf16(                    \
                af[1][i_], BF[1][j_], ACC[(IB) + i_][j_], 0, 0, 0);                          \
        }                                                                                    \
        __builtin_amdgcn_s_setprio(0);                                                       \
    } while (0)

#define ITER1(t, FULL, G4, G8)                                                               \
    do {                                                                                     \
        /* ph1: q(mh0,h) of tile t (X) */                                                    \
        RDA1(X1, 0); RDBH1(X1);                                                              \
        ST1A(Y1, (t) + 1, 1, 0); ST1A(Y1, (t) + 1, 1, 1);                                    \
        BAR(); LGKM0(); MM1(acch, 0, bh); BAR();                                             \
        /* ph2: q(mh0,g) */                                                                  \
        RDBG1(X1);                                                                           \
        if (FULL) { ST1H(X1, (t) + 2, 0); ST1H(X1, (t) + 2, 1); }                            \
        BAR(); LGKM0(); MM1(accg, 0, bg); BAR();                                             \
        /* ph3: q(mh1,h) */                                                                  \
        RDA1(X1, 1);                                                                         \
        if (FULL) { ST1G(X1, (t) + 2, 0); ST1G(X1, (t) + 2, 1); }                            \
        BAR(); LGKM0(); MM1(acch, 4, bh); BAR();                                             \
        /* ph4: q(mh1,g); gate */                                                            \
        if (FULL) { ST1A(X1, (t) + 2, 0, 0); ST1A(X1, (t) + 2, 0, 1); }                      \
        VMCNT(G4); BAR(); MM1(accg, 4, bg); BAR();                                           \
        /* ph5: q(mh0,h) of tile t+1 (Y) */                                                  \
        RDA1(Y1, 0); RDBH1(Y1);                                                              \
        if (FULL) { ST1A(X1, (t) + 2, 1, 0); ST1A(X1, (t) + 2, 1, 1); }                      \
        BAR(); LGKM0(); MM1(acch, 0, bh); BAR();                                             \
        /* ph6: q(mh0,g) */                                                                  \
        RDBG1(Y1);                                                                           \
        if (FULL) { ST1H(Y1, (t) + 3, 0); ST1H(Y1, (t) + 3, 1); }                            \
        BAR(); LGKM0(); MM1(accg, 0, bg); BAR();                                             \
        /* ph7: q(mh1,h) */                                                                  \
        RDA1(Y1, 1);                                                                         \
        if (FULL) { ST1G(Y1, (t) + 3, 0); ST1G(Y1, (t) + 3, 1); }                            \
        BAR(); LGKM0(); MM1(acch, 4, bh); BAR();                                             \
        /* ph8: q(mh1,g); gate */                                                            \
        if (FULL) { ST1A(Y1, (t) + 3, 0, 0); ST1A(Y1, (t) + 3, 0, 1); }                      \
        VMCNT(G8); BAR(); MM1(accg, 4, bg); BAR();                                           \
    } while (0)

    // prologue: 7 half-tiles; vmcnt(6) -> tile0's 4 halves landed
    ST1H(X1, 0, 0); ST1H(X1, 0, 1);        // Bh(0)
    ST1G(X1, 0, 0); ST1G(X1, 0, 1);        // Bg(0)
    ST1A(X1, 0, 0, 0); ST1A(X1, 0, 0, 1);  // A0(0)
    ST1A(X1, 0, 1, 0); ST1A(X1, 0, 1, 1);  // A1(0)
    ST1H(Y1, 1, 0); ST1H(Y1, 1, 1);        // Bh(1)
    ST1G(Y1, 1, 0); ST1G(Y1, 1, 1);        // Bg(1)
    ST1A(Y1, 1, 0, 0); ST1A(Y1, 1, 0, 1);  // A0(1)
    VMCNT(6); BAR();
#pragma unroll 1
    for (int it = 0; it < 7; ++it) ITER1(2 * it, 1, 6, 6);
    ITER1(14, 0, 0, 6);  // tiles 14,15; ph1 stages A1(15); ph4 drains all

    __syncthreads();  // staging LDS dead; reuse as avl [256][128] u32 = 128 KB

    uint32_t* avl = (uint32_t*)smem16;
    const int r0row = (lane >> 4) * 4;
#pragma unroll
    for (int i = 0; i < 8; ++i) {
#pragma unroll
        for (int r = 0; r < 4; ++r) {
            const int row = wr * 128 + i * 16 + r0row + r;
#pragma unroll
            for (int j = 0; j < 2; ++j) {
                const int col = wc * 32 + j * 16 + fr;
                float h = acch[i][j][r];
                float g = accg[i][j][r];
                g = fminf(fmaxf(g, -30.f), 30.f);
                float e = __expf(-g);
                float z = 1.f / (1.f + e);
                float a = e * z;                       // 1 - sigmoid(g)
                float v = z * (fmaxf(h, 0.f) + 0.5f);  // sigmoid(g)*(relu(h)+0.5)
                uint32_t pk = f2bf_bits(a) | (f2bf_bits(v) << 16);
                avl[row * 128 + col] = pk;
                __builtin_nontemporal_store(pk, &av[(m0 + row) * 2048 + n0 + col]);
            }
        }
    }
    __syncthreads();

    // in-block chunk-summary scan: block covers 2 chunks of 128 rows
    const int chl = tid >> 8;  // chunk-local 0/1
    const int t2 = tid & 255;
    const int col = t2 & 127;
    const int rlo = (t2 >> 7) * 64;
    float Aa = 1.f, Vv = 0.f;
#pragma unroll 8
    for (int j = 0; j < 64; ++j) {
        uint32_t pk = avl[(chl * 128 + rlo + j) * 128 + col];
        float a = bflo(pk), v = bfhi(pk);
        Vv = fmaf(a, Vv, v);
        Aa *= a;
    }
    __syncthreads();
    if (rlo == 0) {
        avl[chl * 256 + col] = __float_as_uint(Aa);
        avl[chl * 256 + 128 + col] = __float_as_uint(Vv);
    }
    __syncthreads();
    if (rlo != 0) {
        float Al = __uint_as_float(avl[chl * 256 + col]);
        float Vl = __uint_as_float(avl[chl * 256 + 128 + col]);
        float At = Al * Aa;
        float Vt = fmaf(Aa, Vl, Vv);
        const int chunk = (int)(m0 >> 7) + chl;  // global chunk id = b*32+ch
        sumAV[(size_t)chunk * 2048 + n0 + col] = (float2){At, Vt};
    }
#undef ST1A
#undef ST1H
#undef ST1G
#undef RDA1
#undef RDBH1
#undef RDBG1
#undef MM1
#undef ITER1
}

// ============================================================
// GEMM2 (R15 = R14, loop untouched): 8-phase 256x256 template +
// non-temporal C stores. grid (4, 64) = 256 blocks.
// ============================================================
__global__ __launch_bounds__(512, 2) void gemm2_k(const u16* __restrict__ A,
                                                  const u16* __restrict__ Bt,
                                                  float* __restrict__ C) {
    const int N = DIMX, K = DIM_INNER;
    __shared__ alignas(16) u16 smem16[65536];  // 128 KB
    const int tid = threadIdx.x;
    const int lane = tid & 63;
    const int w = tid >> 6;
    const int wr = w >> 2;
    const int wc = w & 3;
    const size_t m0 = (size_t)blockIdx.y * 256;
    const size_t n0 = (size_t)blockIdx.x * 256;

    floatx4 acc[8][4];
#pragma unroll
    for (int i = 0; i < 8; ++i)
#pragma unroll
        for (int j = 0; j < 4; ++j) acc[i][j] = (floatx4){0.f, 0.f, 0.f, 0.f};

    const int fr = lane & 15;
    const int kb = lane >> 4;
    const int sw0 = kb ^ (fr & 7);
    const int a0 = (wr * 128 + fr) * 64 + sw0 * 8;
    const int a1 = a0 ^ 32;
    const int b0 = 16384 + (wc * 64 + fr) * 64 + sw0 * 8;
    const int b1 = b0 ^ 32;

    const int sr = lane >> 3;
    const int sswz = (lane & 7) ^ sr;
    const u16* pA = A + (m0 + w * 8 + sr) * K + sswz * 8;
    const u16* pB = Bt + (n0 + w * 8 + sr) * K + sswz * 8;

#define ST2A(bufb, kt, h, l)                                                        \
    __builtin_amdgcn_global_load_lds(                                               \
        GCAST(pA + (size_t)((h) * 128 + (l) * 64) * K + (kt) * 64),                 \
        LCAST(smem16 + (bufb) + (h) * 8192 + (l) * 4096 + w * 512), 16, 0, 0)
#define ST2B(bufb, kt, h, l)                                                        \
    __builtin_amdgcn_global_load_lds(                                               \
        GCAST(pB + (size_t)((h) * 128 + (l) * 64) * K + (kt) * 64),                 \
        LCAST(smem16 + (bufb) + 16384 + (h) * 8192 + (l) * 4096 + w * 512), 16, 0, 0)

    short8 af[2][4], ba[2][2], bb[2][2];
#define RDA2(bufb, mh)                                                  \
    do {                                                                \
        _Pragma("unroll") for (int i_ = 0; i_ < 4; ++i_) {              \
            af[0][i_] = LDS8((bufb) + a0 + ((mh) * 4 + i_) * 1024);     \
            af[1][i_] = LDS8((bufb) + a1 + ((mh) * 4 + i_) * 1024);     \
        }                                                               \
    } while (0)
#define RDB2(bufb, BF, nh)                                                  \
    do {                                                                    \
        _Pragma("unroll") for (int j_ = 0; j_ < 2; ++j_) {                  \
            BF[0][j_] = LDS8((bufb) + b0 + ((nh) * 2 + j_) * 1024);         \
            BF[1][j_] = LDS8((bufb) + b1 + ((nh) * 2 + j_) * 1024);         \
        }                                                                   \
    } while (0)
#define MM2(IB, JB, BF)                                                                      \
    do {                                                                                     \
        __builtin_amdgcn_s_setprio(1);                                                       \
        _Pragma("unroll") for (int i_ = 0; i_ < 4; ++i_)                                     \
            _Pragma("unroll") for (int j_ = 0; j_ < 2; ++j_) {                               \
            acc[(IB) + i_][(JB) + j_] = __builtin_amdgcn_mfma_f32_16x16x32_bf16(             \
                af[0][i_], BF[0][j_], acc[(IB) + i_][(JB) + j_], 0, 0, 0);                   \
            acc[(IB) + i_][(JB) + j_] = __builtin_amdgcn_mfma_f32_16x16x32_bf16(             \
                af[1][i_], BF[1][j_], acc[(IB) + i_][(JB) + j_], 0, 0, 0);                   \
        }                                                                                    \
        __builtin_amdgcn_s_setprio(0);                                                       \
    } while (0)

#define ITER2(t, FULL, G4, G8)                                                               \
    do {                                                                                     \
        /* ph1 */ RDA2(X1, 0); RDB2(X1, ba, 0);                                              \
        ST2A(Y1, (t) + 1, 0, 0); ST2A(Y1, (t) + 1, 0, 1);                                    \
        BAR(); LGKM0(); MM2(0, 0, ba); BAR();                                                \
        /* ph2 */ RDB2(X1, bb, 1);                                                           \
        ST2A(Y1, (t) + 1, 1, 0); ST2A(Y1, (t) + 1, 1, 1);                                    \
        BAR(); LGKM0(); MM2(0, 2, bb); BAR();                                                \
        /* ph3 */ RDA2(X1, 1);                                                               \
        if (FULL) { ST2B(X1, (t) + 2, 0, 0); ST2B(X1, (t) + 2, 0, 1); }                      \
        BAR(); LGKM0(); MM2(4, 0, ba); BAR();                                                \
        /* ph4 */                                                                            \
        if (FULL) { ST2B(X1, (t) + 2, 1, 0); ST2B(X1, (t) + 2, 1, 1); }                      \
        VMCNT(G4); BAR(); MM2(4, 2, bb); BAR();                                              \
        /* ph5 */ RDA2(Y1, 0); RDB2(Y1, ba, 0);                                              \
        if (FULL) { ST2A(X1, (t) + 2, 0, 0); ST2A(X1, (t) + 2, 0, 1); }                      \
        BAR(); LGKM0(); MM2(0, 0, ba); BAR();                                                \
        /* ph6 */ RDB2(Y1, bb, 1);                                                           \
        if (FULL) { ST2A(X1, (t) + 2, 1, 0); ST2A(X1, (t) + 2, 1, 1); }                      \
        BAR(); LGKM0(); MM2(0, 2, bb); BAR();                                                \
        /* ph7 */ RDA2(Y1, 1);                                                               \
        if (FULL) { ST2B(Y1, (t) + 3, 0, 0); ST2B(Y1, (t) + 3, 0, 1); }                      \
        BAR(); LGKM0(); MM2(4, 0, ba); BAR();                                                \
        /* ph8 */                                                                            \
        if (FULL) { ST2B(Y1, (t) + 3, 1, 0); ST2B(Y1, (t) + 3, 1, 1); }                      \
        VMCNT(G8); BAR(); MM2(4, 2, bb); BAR();                                              \
    } while (0)

    // prologue: 6 half-tiles; vmcnt(4) -> tile0's 4 halves landed
    ST2B(X1, 0, 0, 0); ST2B(X1, 0, 0, 1);  // B0(0)
    ST2B(X1, 0, 1, 0); ST2B(X1, 0, 1, 1);  // B1(0)
    ST2A(X1, 0, 0, 0); ST2A(X1, 0, 0, 1);  // A0(0)
    ST2A(X1, 0, 1, 0); ST2A(X1, 0, 1, 1);  // A1(0)
    ST2B(Y1, 1, 0, 0); ST2B(Y1, 1, 0, 1);  // B0(1)
    ST2B(Y1, 1, 1, 0); ST2B(Y1, 1, 1, 1);  // B1(1)
    VMCNT(4); BAR();
#pragma unroll 1
    for (int it = 0; it < 15; ++it) ITER2(2 * it, 1, 4, 4);
    ITER2(30, 0, 0, 4);  // tiles 30,31; ph1/ph2 stage A(31); ph4 drains all

    const int r0row = (lane >> 4) * 4;
#pragma unroll
    for (int i = 0; i < 8; ++i)
#pragma unroll
        for (int r = 0; r < 4; ++r) {
            size_t row = m0 + wr * 128 + i * 16 + r0row + r;
#pragma unroll
            for (int j = 0; j < 4; ++j) {
                size_t col = n0 + wc * 64 + j * 16 + fr;
                __builtin_nontemporal_store(acc[i][j][r], &C[row * N + col]);
            }
        }
#undef ST2A
#undef ST2B
#undef RDA2
#undef RDB2
#undef MM2
#undef ITER2
}

// ============================================================
// Phase B+C merged (R15): per-block carry recompute from sumAV
// (bit-identical fmaf chain to the old scan_carry), then replay chunk
// from packed (a,v) with nt loads, emit h bf16.
// grid (4, NCHUNK, BATCH) x 256; thread -> 2 channels.
// ============================================================
__global__ __launch_bounds__(256) void scan_apply(const uint32_t* __restrict__ av,
                                                  const float2* __restrict__ sumAV,
                                                  uint32_t* __restrict__ hbuf) {
    const int b = blockIdx.z, ch = blockIdx.y;
    const int c2 = blockIdx.x * 256 + threadIdx.x;  // channel-pair 0..1023
    const size_t rowbase = (size_t)b * SEQ + (size_t)ch * CLEN;
    const uint32_t* p = av + rowbase * 2048 + c2 * 2;
    uint32_t* q = hbuf + rowbase * 1024 + c2;

    // exclusive carry over chunk summaries (identical op order to old scan_carry)
    float h0 = 0.f, h1 = 0.f;
    const float4* sp = (const float4*)sumAV + (size_t)b * NCHUNK * 1024 + c2;
    for (int cc = 0; cc < ch; ++cc) {
        float4 s = sp[(size_t)cc * 1024];
        h0 = fmaf(s.x, h0, s.y);
        h1 = fmaf(s.z, h1, s.w);
    }

    u32x2 buf[4];
#pragma unroll
    for (int t = 0; t < 4; ++t)
        buf[t] = __builtin_nontemporal_load((const u32x2*)(p + (size_t)t * 2048));

    for (int j0 = 0; j0 < CLEN; j0 += 4) {
        u32x2 nxt[4];
        if (j0 + 4 < CLEN) {
#pragma unroll
            for (int t = 0; t < 4; ++t)
                nxt[t] = __builtin_nontemporal_load((const u32x2*)(p + (size_t)(j0 + 4 + t) * 2048));
        }
#pragma unroll
        for (int t = 0; t < 4; ++t) {
            float a0 = bflo(buf[t].x), v0 = bfhi(buf[t].x);
            float a1 = bflo(buf[t].y), v1 = bfhi(buf[t].y);
            h0 = fmaf(a0, h0, v0);
            h1 = fmaf(a1, h1, v1);
            q[(size_t)(j0 + t) * 1024] = f2bf_bits(h0) | (f2bf_bits(h1) << 16);
        }
#pragma unroll
        for (int t = 0; t < 4; ++t) buf[t] = nxt[t];
    }
}

// ============================================================
extern "C" void kernel_launch(void* const* d_in, const int* in_sizes, int n_in,
                              void* d_out, int out_size, void* d_ws, size_t ws_size,
                              hipStream_t stream) {
    const float* x = (const float*)d_in[0];     // [16384,1024]
    const float* Whg = (const float*)d_in[1];   // [1024,4096]
    const float* Wout = (const float*)d_in[2];  // [2048,1024]

    char* ws = (char*)d_ws;
    size_t off = 0;
    u16* xb = (u16*)(ws + off);        off += (size_t)M_TOTAL * DIMX * 2;          // 33.6 MB
    u16* whgt = (u16*)(ws + off);      off += (size_t)N_HG * DIMX * 2;             // 8.4 MB
    u16* woutt = (u16*)(ws + off);     off += (size_t)DIMX * DIM_INNER * 2;        // 4.2 MB
    uint32_t* av = (uint32_t*)(ws + off); off += (size_t)M_TOTAL * DIM_INNER * 4;  // 134.2 MB
    uint32_t* hbuf = (uint32_t*)(ws + off); off += (size_t)M_TOTAL * DIM_INNER * 2; // 67.1 MB
    float2* sumAV = (float2*)(ws + off); off += (size_t)BATCH * NCHUNK * DIM_INNER * 8; // 2.1 MB

    // 1. fused prep
    prep<<<2048 + 1024 + 512, 256, 0, stream>>>(x, Whg, Wout, xb, whgt, woutt);

    // 2. GEMM1 fused (8-phase + XCD remap + nt av): av + per-chunk summaries
    gemm1_k<<<1024, 512, 0, stream>>>(xb, whgt, av, sumAV);

    // 3. merged carry+replay
    scan_apply<<<dim3(4, NCHUNK, BATCH), 256, 0, stream>>>(av, sumAV, hbuf);

    // 4. GEMM2 (8-phase + nt C): out = h @ Wout (fp32 out), 256x256 tiles
    gemm2_k<<<dim3(DIMX / 256, M_TOTAL / 256), 512, 0, stream>>>((const u16*)hbuf, woutt, (float*)d_out);
}

// Round 7
// 380.867 us; speedup vs baseline: 1.0028x; 1.0028x over previous
//
#include <hip/hip_runtime.h>
#include <stdint.h>

// ---- problem constants ----
#define DIMX 1024
#define DIM_INNER 2048
#define BATCH 4
#define SEQ 4096
#define M_TOTAL (BATCH * SEQ)   // 16384
#define N_HG (2 * DIM_INNER)    // 4096
#define NCHUNK 32               // chunks along S
#define CLEN 128                // steps per chunk

typedef unsigned short u16;
typedef __attribute__((ext_vector_type(8))) short short8;   // 8 x bf16 MFMA frag
typedef __attribute__((ext_vector_type(4))) float floatx4;  // MFMA acc
typedef __attribute__((ext_vector_type(2))) unsigned int u32x2;

// ---- bf16 helpers (bit-level, RNE) ----
__device__ __forceinline__ float bflo(uint32_t u) { return __uint_as_float(u << 16); }
__device__ __forceinline__ float bfhi(uint32_t u) { return __uint_as_float(u & 0xffff0000u); }
__device__ __forceinline__ uint32_t f2bf_bits(float f) {
    uint32_t u = __float_as_uint(f);
    return (u + 0x7fffu + ((u >> 16) & 1u)) >> 16;  // round-to-nearest-even
}

#define GCAST(p) (const __attribute__((address_space(1))) uint32_t*)(const void*)(p)
#define LCAST(p) (__attribute__((address_space(3))) uint32_t*)(void*)(p)
// raw barrier + IR-level fence (plain LDS loads may not cross)
#define BAR()                                          \
    do {                                               \
        __builtin_amdgcn_s_barrier();                  \
        asm volatile("" ::: "memory");                 \
    } while (0)
// drain this wave's ds_reads before the phase's MFMA + pin scheduling (rule #18)
#define LGKM0()                                                  \
    do {                                                         \
        asm volatile("s_waitcnt lgkmcnt(0)" ::: "memory");       \
        __builtin_amdgcn_sched_barrier(0);                       \
    } while (0)
#define VMCNT_(n) asm volatile("s_waitcnt vmcnt(" #n ")" ::: "memory")
#define VMCNT(n) VMCNT_(n)

// ============================================================
// prep kernel: fuses x-cast + Whg transpose + Wout transpose. (unchanged)
// ============================================================
__global__ __launch_bounds__(256) void prep(const float* __restrict__ x,
                                            const float* __restrict__ Whg,
                                            const float* __restrict__ Wout,
                                            u16* __restrict__ xb,
                                            u16* __restrict__ whgt,
                                            u16* __restrict__ woutt) {
    __shared__ float tile[64][65];
    const int bid = blockIdx.x;
    const int tid = threadIdx.x;
    if (bid < 2048) {
        const int n4 = M_TOTAL * DIMX / 4;
        const float4* in4 = (const float4*)x;
        ushort4* out4 = (ushort4*)xb;
        for (int i = bid * 256 + tid; i < n4; i += 2048 * 256) {
            float4 v = in4[i];
            ushort4 o;
            o.x = (u16)f2bf_bits(v.x);
            o.y = (u16)f2bf_bits(v.y);
            o.z = (u16)f2bf_bits(v.z);
            o.w = (u16)f2bf_bits(v.w);
            out4[i] = o;
        }
        return;
    }
    const float* in;
    u16* out;
    int R, C, tb;
    if (bid < 3072) {
        in = Whg; out = whgt; R = DIMX; C = N_HG; tb = bid - 2048;
    } else {
        in = Wout; out = woutt; R = DIM_INNER; C = DIMX; tb = bid - 3072;
    }
    const int tilesx = C / 64;
    const int c0 = (tb % tilesx) * 64, r0 = (tb / tilesx) * 64;
    const int tx = tid & 63, ty = tid >> 6;  // 64 x 4
#pragma unroll
    for (int i = ty; i < 64; i += 4)
        tile[i][tx] = in[(size_t)(r0 + i) * C + c0 + tx];
    __syncthreads();
#pragma unroll
    for (int i = ty; i < 64; i += 4)
        out[(size_t)(c0 + i) * R + r0 + tx] = (u16)f2bf_bits(tile[tx][i]);
}

// ============================================================
// GEMM1 fused (R16 = R13 exactly: 8-phase + XCD remap, plain av stores).
// nt stores reverted: av must stay L2/L3-resident for scan_apply.
// grid 1024 blocks (1D).
// ============================================================
__global__ __launch_bounds__(512, 2) void gemm1_k(const u16* __restrict__ A,
                                                  const u16* __restrict__ Bt,
                                                  uint32_t* __restrict__ av,
                                                  float2* __restrict__ sumAV) {
    __shared__ alignas(16) u16 smem16[65536];  // 128 KB
    const int tid = threadIdx.x;
    const int lane = tid & 63;
    const int w = tid >> 6;
    const int wr = w >> 2;
    const int wc = w & 3;
    // T1 XCD-aware bijective remap (1024 blocks, 8 XCDs)
    const int wgid = blockIdx.x;
    const int xcd = wgid & 7;
    const int idx = wgid >> 3;          // 0..127
    const int xt = idx & 15;            // column tile 0..15
    const int yt = (idx >> 4) * 8 + xcd; // row tile 0..63, yt%8 == xcd
    const size_t m0 = (size_t)yt * 256;
    const int n0 = xt * 128;
#define X1 0
#define Y1 32768

    floatx4 acch[8][2], accg[8][2];
#pragma unroll
    for (int i = 0; i < 8; ++i)
#pragma unroll
        for (int j = 0; j < 2; ++j) {
            acch[i][j] = (floatx4){0.f, 0.f, 0.f, 0.f};
            accg[i][j] = (floatx4){0.f, 0.f, 0.f, 0.f};
        }

    // fragment addressing (u16 indices); row stride 64 u16, slot = 8 u16 (16B)
    const int fr = lane & 15;
    const int kb = lane >> 4;
    const int sw0 = kb ^ (fr & 7);                       // swizzled slot, kstep 0
    const int a0 = (wr * 128 + fr) * 64 + sw0 * 8;       // kstep1 = a0 ^ 32
    const int a1 = a0 ^ 32;
    const int b0 = 16384 + (wc * 32 + fr) * 64 + sw0 * 8;
    const int b1 = b0 ^ 32;

    // staging: lane covers (row = 8w + lane>>3, slot' = lane&7); global slot
    // = slot' ^ (row&7) = (lane&7)^(lane>>3). LDS dest stays linear.
    const int sr = lane >> 3;
    const int sswz = (lane & 7) ^ sr;
    const u16* pA = A + (m0 + w * 8 + sr) * DIMX + sswz * 8;
    const u16* pBh = Bt + ((size_t)(n0 + w * 8 + sr)) * DIMX + sswz * 8;
    const u16* pBg = pBh + (size_t)DIM_INNER * DIMX;

#define ST1A(bufb, kt, h, l)                                                        \
    __builtin_amdgcn_global_load_lds(                                               \
        GCAST(pA + (size_t)((h) * 128 + (l) * 64) * DIMX + (kt) * 64),              \
        LCAST(smem16 + (bufb) + (h) * 8192 + (l) * 4096 + w * 512), 16, 0, 0)
#define ST1H(bufb, kt, l)                                                           \
    __builtin_amdgcn_global_load_lds(                                               \
        GCAST(pBh + (size_t)((l) * 64) * DIMX + (kt) * 64),                         \
        LCAST(smem16 + (bufb) + 16384 + (l) * 4096 + w * 512), 16, 0, 0)
#define ST1G(bufb, kt, l)                                                           \
    __builtin_amdgcn_global_load_lds(                                               \
        GCAST(pBg + (size_t)((l) * 64) * DIMX + (kt) * 64),                         \
        LCAST(smem16 + (bufb) + 24576 + (l) * 4096 + w * 512), 16, 0, 0)

#define LDS8(idx) (*(const short8*)(smem16 + (idx)))
    short8 af[2][4], bh[2][2], bg[2][2];
#define RDA1(bufb, mh)                                                  \
    do {                                                                \
        _Pragma("unroll") for (int i_ = 0; i_ < 4; ++i_) {              \
            af[0][i_] = LDS8((bufb) + a0 + ((mh) * 4 + i_) * 1024);     \
            af[1][i_] = LDS8((bufb) + a1 + ((mh) * 4 + i_) * 1024);     \
        }                                                               \
    } while (0)
#define RDBH1(bufb)                                                     \
    do {                                                                \
        _Pragma("unroll") for (int j_ = 0; j_ < 2; ++j_) {              \
            bh[0][j_] = LDS8((bufb) + b0 + j_ * 1024);                  \
            bh[1][j_] = LDS8((bufb) + b1 + j_ * 1024);                  \
        }                                                               \
    } while (0)
#define RDBG1(bufb)                                                     \
    do {                                                                \
        _Pragma("unroll") for (int j_ = 0; j_ < 2; ++j_) {              \
            bg[0][j_] = LDS8((bufb) + b0 + 8192 + j_ * 1024);           \
            bg[1][j_] = LDS8((bufb) + b1 + 8192 + j_ * 1024);           \
        }                                                               \
    } while (0)
#define MM1(ACC, IB, BF)                                                                     \
    do {                                                                                     \
        __builtin_amdgcn_s_setprio(1);                                                       \
        _Pragma("unroll") for (int i_ = 0; i_ < 4; ++i_)                                     \
            _Pragma("unroll") for (int j_ = 0; j_ < 2; ++j_) {                               \
            ACC[(IB) + i_][j_] = __builtin_amdgcn_mfma_f32_16x16x32_bf16(                    \
                af[0][i_], BF[0][j_], ACC[(IB) + i_][j_], 0, 0, 0);                          \
            ACC[(IB) + i_][j_] = __builtin_amdgcn_mfma_f32_16x16x32_bf16(                    \
                af[1][i_], BF[1][j_], ACC[(IB) + i_][j_], 0, 0, 0);                          \
        }                                                                                    \
        __builtin_amdgcn_s_setprio(0);                                                       \
    } while (0)

#define ITER1(t, FULL, G4, G8)                                                               \
    do {                                                                                     \
        /* ph1: q(mh0,h) of tile t (X) */                                                    \
        RDA1(X1, 0); RDBH1(X1);                                                              \
        ST1A(Y1, (t) + 1, 1, 0); ST1A(Y1, (t) + 1, 1, 1);                                    \
        BAR(); LGKM0(); MM1(acch, 0, bh); BAR();                                             \
        /* ph2: q(mh0,g) */                                                                  \
        RDBG1(X1);                                                                           \
        if (FULL) { ST1H(X1, (t) + 2, 0); ST1H(X1, (t) + 2, 1); }                            \
        BAR(); LGKM0(); MM1(accg, 0, bg); BAR();                                             \
        /* ph3: q(mh1,h) */                                                                  \
        RDA1(X1, 1);                                                                         \
        if (FULL) { ST1G(X1, (t) + 2, 0); ST1G(X1, (t) + 2, 1); }                            \
        BAR(); LGKM0(); MM1(acch, 4, bh); BAR();                                             \
        /* ph4: q(mh1,g); gate */                                                            \
        if (FULL) { ST1A(X1, (t) + 2, 0, 0); ST1A(X1, (t) + 2, 0, 1); }                      \
        VMCNT(G4); BAR(); MM1(accg, 4, bg); BAR();                                           \
        /* ph5: q(mh0,h) of tile t+1 (Y) */                                                  \
        RDA1(Y1, 0); RDBH1(Y1);                                                              \
        if (FULL) { ST1A(X1, (t) + 2, 1, 0); ST1A(X1, (t) + 2, 1, 1); }                      \
        BAR(); LGKM0(); MM1(acch, 0, bh); BAR();                                             \
        /* ph6: q(mh0,g) */                                                                  \
        RDBG1(Y1);                                                                           \
        if (FULL) { ST1H(Y1, (t) + 3, 0); ST1H(Y1, (t) + 3, 1); }                            \
        BAR(); LGKM0(); MM1(accg, 0, bg); BAR();                                             \
        /* ph7: q(mh1,h) */                                                                  \
        RDA1(Y1, 1);                                                                         \
        if (FULL) { ST1G(Y1, (t) + 3, 0); ST1G(Y1, (t) + 3, 1); }                            \
        BAR(); LGKM0(); MM1(acch, 4, bh); BAR();                                             \
        /* ph8: q(mh1,g); gate */                                                            \
        if (FULL) { ST1A(Y1, (t) + 3, 0, 0); ST1A(Y1, (t) + 3, 0, 1); }                      \
        VMCNT(G8); BAR(); MM1(accg, 4, bg); BAR();                                           \
    } while (0)

    // prologue: 7 half-tiles; vmcnt(6) -> tile0's 4 halves landed
    ST1H(X1, 0, 0); ST1H(X1, 0, 1);        // Bh(0)
    ST1G(X1, 0, 0); ST1G(X1, 0, 1);        // Bg(0)
    ST1A(X1, 0, 0, 0); ST1A(X1, 0, 0, 1);  // A0(0)
    ST1A(X1, 0, 1, 0); ST1A(X1, 0, 1, 1);  // A1(0)
    ST1H(Y1, 1, 0); ST1H(Y1, 1, 1);        // Bh(1)
    ST1G(Y1, 1, 0); ST1G(Y1, 1, 1);        // Bg(1)
    ST1A(Y1, 1, 0, 0); ST1A(Y1, 1, 0, 1);  // A0(1)
    VMCNT(6); BAR();
#pragma unroll 1
    for (int it = 0; it < 7; ++it) ITER1(2 * it, 1, 6, 6);
    ITER1(14, 0, 0, 6);  // tiles 14,15; ph1 stages A1(15); ph4 drains all

    __syncthreads();  // staging LDS dead; reuse as avl [256][128] u32 = 128 KB

    uint32_t* avl = (uint32_t*)smem16;
    const int r0row = (lane >> 4) * 4;
#pragma unroll
    for (int i = 0; i < 8; ++i) {
#pragma unroll
        for (int r = 0; r < 4; ++r) {
            const int row = wr * 128 + i * 16 + r0row + r;
#pragma unroll
            for (int j = 0; j < 2; ++j) {
                const int col = wc * 32 + j * 16 + fr;
                float h = acch[i][j][r];
                float g = accg[i][j][r];
                g = fminf(fmaxf(g, -30.f), 30.f);
                float e = __expf(-g);
                float z = 1.f / (1.f + e);
                float a = e * z;                       // 1 - sigmoid(g)
                float v = z * (fmaxf(h, 0.f) + 0.5f);  // sigmoid(g)*(relu(h)+0.5)
                uint32_t pk = f2bf_bits(a) | (f2bf_bits(v) << 16);
                avl[row * 128 + col] = pk;
                av[(m0 + row) * 2048 + n0 + col] = pk;
            }
        }
    }
    __syncthreads();

    // in-block chunk-summary scan: block covers 2 chunks of 128 rows
    const int chl = tid >> 8;  // chunk-local 0/1
    const int t2 = tid & 255;
    const int col = t2 & 127;
    const int rlo = (t2 >> 7) * 64;
    float Aa = 1.f, Vv = 0.f;
#pragma unroll 8
    for (int j = 0; j < 64; ++j) {
        uint32_t pk = avl[(chl * 128 + rlo + j) * 128 + col];
        float a = bflo(pk), v = bfhi(pk);
        Vv = fmaf(a, Vv, v);
        Aa *= a;
    }
    __syncthreads();
    if (rlo == 0) {
        avl[chl * 256 + col] = __float_as_uint(Aa);
        avl[chl * 256 + 128 + col] = __float_as_uint(Vv);
    }
    __syncthreads();
    if (rlo != 0) {
        float Al = __uint_as_float(avl[chl * 256 + col]);
        float Vl = __uint_as_float(avl[chl * 256 + 128 + col]);
        float At = Al * Aa;
        float Vt = fmaf(Aa, Vl, Vv);
        const int chunk = (int)(m0 >> 7) + chl;  // global chunk id = b*32+ch
        sumAV[(size_t)chunk * 2048 + n0 + col] = (float2){At, Vt};
    }
#undef ST1A
#undef ST1H
#undef ST1G
#undef RDA1
#undef RDBH1
#undef RDBG1
#undef MM1
#undef ITER1
}

// ============================================================
// GEMM2 (R16 = R13 exactly: 8-phase 256x256, plain C stores).
// grid (4, 64) = 256 blocks.
// ============================================================
__global__ __launch_bounds__(512, 2) void gemm2_k(const u16* __restrict__ A,
                                                  const u16* __restrict__ Bt,
                                                  float* __restrict__ C) {
    const int N = DIMX, K = DIM_INNER;
    __shared__ alignas(16) u16 smem16[65536];  // 128 KB
    const int tid = threadIdx.x;
    const int lane = tid & 63;
    const int w = tid >> 6;
    const int wr = w >> 2;
    const int wc = w & 3;
    const size_t m0 = (size_t)blockIdx.y * 256;
    const size_t n0 = (size_t)blockIdx.x * 256;

    floatx4 acc[8][4];
#pragma unroll
    for (int i = 0; i < 8; ++i)
#pragma unroll
        for (int j = 0; j < 4; ++j) acc[i][j] = (floatx4){0.f, 0.f, 0.f, 0.f};

    const int fr = lane & 15;
    const int kb = lane >> 4;
    const int sw0 = kb ^ (fr & 7);
    const int a0 = (wr * 128 + fr) * 64 + sw0 * 8;
    const int a1 = a0 ^ 32;
    const int b0 = 16384 + (wc * 64 + fr) * 64 + sw0 * 8;
    const int b1 = b0 ^ 32;

    const int sr = lane >> 3;
    const int sswz = (lane & 7) ^ sr;
    const u16* pA = A + (m0 + w * 8 + sr) * K + sswz * 8;
    const u16* pB = Bt + (n0 + w * 8 + sr) * K + sswz * 8;

#define ST2A(bufb, kt, h, l)                                                        \
    __builtin_amdgcn_global_load_lds(                                               \
        GCAST(pA + (size_t)((h) * 128 + (l) * 64) * K + (kt) * 64),                 \
        LCAST(smem16 + (bufb) + (h) * 8192 + (l) * 4096 + w * 512), 16, 0, 0)
#define ST2B(bufb, kt, h, l)                                                        \
    __builtin_amdgcn_global_load_lds(                                               \
        GCAST(pB + (size_t)((h) * 128 + (l) * 64) * K + (kt) * 64),                 \
        LCAST(smem16 + (bufb) + 16384 + (h) * 8192 + (l) * 4096 + w * 512), 16, 0, 0)

    short8 af[2][4], ba[2][2], bb[2][2];
#define RDA2(bufb, mh)                                                  \
    do {                                                                \
        _Pragma("unroll") for (int i_ = 0; i_ < 4; ++i_) {              \
            af[0][i_] = LDS8((bufb) + a0 + ((mh) * 4 + i_) * 1024);     \
            af[1][i_] = LDS8((bufb) + a1 + ((mh) * 4 + i_) * 1024);     \
        }                                                               \
    } while (0)
#define RDB2(bufb, BF, nh)                                                  \
    do {                                                                    \
        _Pragma("unroll") for (int j_ = 0; j_ < 2; ++j_) {                  \
            BF[0][j_] = LDS8((bufb) + b0 + ((nh) * 2 + j_) * 1024);         \
            BF[1][j_] = LDS8((bufb) + b1 + ((nh) * 2 + j_) * 1024);         \
        }                                                                   \
    } while (0)
#define MM2(IB, JB, BF)                                                                      \
    do {                                                                                     \
        __builtin_amdgcn_s_setprio(1);                                                       \
        _Pragma("unroll") for (int i_ = 0; i_ < 4; ++i_)                                     \
            _Pragma("unroll") for (int j_ = 0; j_ < 2; ++j_) {                               \
            acc[(IB) + i_][(JB) + j_] = __builtin_amdgcn_mfma_f32_16x16x32_bf16(             \
                af[0][i_], BF[0][j_], acc[(IB) + i_][(JB) + j_], 0, 0, 0);                   \
            acc[(IB) + i_][(JB) + j_] = __builtin_amdgcn_mfma_f32_16x16x32_bf16(             \
                af[1][i_], BF[1][j_], acc[(IB) + i_][(JB) + j_], 0, 0, 0);                   \
        }                                                                                    \
        __builtin_amdgcn_s_setprio(0);                                                       \
    } while (0)

#define ITER2(t, FULL, G4, G8)                                                               \
    do {                                                                                     \
        /* ph1 */ RDA2(X1, 0); RDB2(X1, ba, 0);                                              \
        ST2A(Y1, (t) + 1, 0, 0); ST2A(Y1, (t) + 1, 0, 1);                                    \
        BAR(); LGKM0(); MM2(0, 0, ba); BAR();                                                \
        /* ph2 */ RDB2(X1, bb, 1);                                                           \
        ST2A(Y1, (t) + 1, 1, 0); ST2A(Y1, (t) + 1, 1, 1);                                    \
        BAR(); LGKM0(); MM2(0, 2, bb); BAR();                                                \
        /* ph3 */ RDA2(X1, 1);                                                               \
        if (FULL) { ST2B(X1, (t) + 2, 0, 0); ST2B(X1, (t) + 2, 0, 1); }                      \
        BAR(); LGKM0(); MM2(4, 0, ba); BAR();                                                \
        /* ph4 */                                                                            \
        if (FULL) { ST2B(X1, (t) + 2, 1, 0); ST2B(X1, (t) + 2, 1, 1); }                      \
        VMCNT(G4); BAR(); MM2(4, 2, bb); BAR();                                              \
        /* ph5 */ RDA2(Y1, 0); RDB2(Y1, ba, 0);                                              \
        if (FULL) { ST2A(X1, (t) + 2, 0, 0); ST2A(X1, (t) + 2, 0, 1); }                      \
        BAR(); LGKM0(); MM2(0, 0, ba); BAR();                                                \
        /* ph6 */ RDB2(Y1, bb, 1);                                                           \
        if (FULL) { ST2A(X1, (t) + 2, 1, 0); ST2A(X1, (t) + 2, 1, 1); }                      \
        BAR(); LGKM0(); MM2(0, 2, bb); BAR();                                                \
        /* ph7 */ RDA2(Y1, 1);                                                               \
        if (FULL) { ST2B(Y1, (t) + 3, 0, 0); ST2B(Y1, (t) + 3, 0, 1); }                      \
        BAR(); LGKM0(); MM2(4, 0, ba); BAR();                                                \
        /* ph8 */                                                                            \
        if (FULL) { ST2B(Y1, (t) + 3, 1, 0); ST2B(Y1, (t) + 3, 1, 1); }                      \
        VMCNT(G8); BAR(); MM2(4, 2, bb); BAR();                                              \
    } while (0)

    // prologue: 6 half-tiles; vmcnt(4) -> tile0's 4 halves landed
    ST2B(X1, 0, 0, 0); ST2B(X1, 0, 0, 1);  // B0(0)
    ST2B(X1, 0, 1, 0); ST2B(X1, 0, 1, 1);  // B1(0)
    ST2A(X1, 0, 0, 0); ST2A(X1, 0, 0, 1);  // A0(0)
    ST2A(X1, 0, 1, 0); ST2A(X1, 0, 1, 1);  // A1(0)
    ST2B(Y1, 1, 0, 0); ST2B(Y1, 1, 0, 1);  // B0(1)
    ST2B(Y1, 1, 1, 0); ST2B(Y1, 1, 1, 1);  // B1(1)
    VMCNT(4); BAR();
#pragma unroll 1
    for (int it = 0; it < 15; ++it) ITER2(2 * it, 1, 4, 4);
    ITER2(30, 0, 0, 4);  // tiles 30,31; ph1/ph2 stage A(31); ph4 drains all

    const int r0row = (lane >> 4) * 4;
#pragma unroll
    for (int i = 0; i < 8; ++i)
#pragma unroll
        for (int r = 0; r < 4; ++r) {
            size_t row = m0 + wr * 128 + i * 16 + r0row + r;
#pragma unroll
            for (int j = 0; j < 4; ++j) {
                size_t col = n0 + wc * 64 + j * 16 + fr;
                C[row * N + col] = acc[i][j][r];
            }
        }
#undef ST2A
#undef ST2B
#undef RDA2
#undef RDB2
#undef MM2
#undef ITER2
}

// ============================================================
// Phase B+C merged (R16): carry recompute from sumAV (bit-identical fmaf
// chain), then replay with 16-deep row prefetch (128 B/thread in flight;
// was 4-deep = latency-bound at ~1.5 TB/s). Plain (cached) loads.
// grid (4, NCHUNK, BATCH) x 256; thread -> 2 channels.
// ============================================================
__global__ __launch_bounds__(256) void scan_apply(const uint32_t* __restrict__ av,
                                                  const float2* __restrict__ sumAV,
                                                  uint32_t* __restrict__ hbuf) {
    const int b = blockIdx.z, ch = blockIdx.y;
    const int c2 = blockIdx.x * 256 + threadIdx.x;  // channel-pair 0..1023
    const size_t rowbase = (size_t)b * SEQ + (size_t)ch * CLEN;
    const uint32_t* p = av + rowbase * 2048 + c2 * 2;
    uint32_t* q = hbuf + rowbase * 1024 + c2;

    // exclusive carry over chunk summaries (identical op order to old scan_carry)
    float h0 = 0.f, h1 = 0.f;
    const float4* sp = (const float4*)sumAV + (size_t)b * NCHUNK * 1024 + c2;
    for (int cc = 0; cc < ch; ++cc) {
        float4 s = sp[(size_t)cc * 1024];
        h0 = fmaf(s.x, h0, s.y);
        h1 = fmaf(s.z, h1, s.w);
    }

    u32x2 buf[16];
#pragma unroll
    for (int t = 0; t < 16; ++t) buf[t] = *(const u32x2*)(p + (size_t)t * 2048);

    for (int j0 = 0; j0 < CLEN; j0 += 16) {
        u32x2 nxt[16];
        if (j0 + 16 < CLEN) {
#pragma unroll
            for (int t = 0; t < 16; ++t)
                nxt[t] = *(const u32x2*)(p + (size_t)(j0 + 16 + t) * 2048);
        }
#pragma unroll
        for (int t = 0; t < 16; ++t) {
            float a0 = bflo(buf[t].x), v0 = bfhi(buf[t].x);
            float a1 = bflo(buf[t].y), v1 = bfhi(buf[t].y);
            h0 = fmaf(a0, h0, v0);
            h1 = fmaf(a1, h1, v1);
            q[(size_t)(j0 + t) * 1024] = f2bf_bits(h0) | (f2bf_bits(h1) << 16);
        }
#pragma unroll
        for (int t = 0; t < 16; ++t) buf[t] = nxt[t];
    }
}

// ============================================================
extern "C" void kernel_launch(void* const* d_in, const int* in_sizes, int n_in,
                              void* d_out, int out_size, void* d_ws, size_t ws_size,
                              hipStream_t stream) {
    const float* x = (const float*)d_in[0];     // [16384,1024]
    const float* Whg = (const float*)d_in[1];   // [1024,4096]
    const float* Wout = (const float*)d_in[2];  // [2048,1024]

    char* ws = (char*)d_ws;
    size_t off = 0;
    u16* xb = (u16*)(ws + off);        off += (size_t)M_TOTAL * DIMX * 2;          // 33.6 MB
    u16* whgt = (u16*)(ws + off);      off += (size_t)N_HG * DIMX * 2;             // 8.4 MB
    u16* woutt = (u16*)(ws + off);     off += (size_t)DIMX * DIM_INNER * 2;        // 4.2 MB
    uint32_t* av = (uint32_t*)(ws + off); off += (size_t)M_TOTAL * DIM_INNER * 4;  // 134.2 MB
    uint32_t* hbuf = (uint32_t*)(ws + off); off += (size_t)M_TOTAL * DIM_INNER * 2; // 67.1 MB
    float2* sumAV = (float2*)(ws + off); off += (size_t)BATCH * NCHUNK * DIM_INNER * 8; // 2.1 MB

    // 1. fused prep
    prep<<<2048 + 1024 + 512, 256, 0, stream>>>(x, Whg, Wout, xb, whgt, woutt);

    // 2. GEMM1 fused (8-phase + XCD remap): av + per-chunk summaries
    gemm1_k<<<1024, 512, 0, stream>>>(xb, whgt, av, sumAV);

    // 3. merged carry+replay (16-deep prefetch)
    scan_apply<<<dim3(4, NCHUNK, BATCH), 256, 0, stream>>>(av, sumAV, hbuf);

    // 4. GEMM2 (8-phase): out = h @ Wout (fp32 out), 256x256 tiles
    gemm2_k<<<dim3(DIMX / 256, M_TOTAL / 256), 512, 0, stream>>>((const u16*)hbuf, woutt, (float*)d_out);
}

// Round 8
// 369.948 us; speedup vs baseline: 1.0324x; 1.0295x over previous
//
#include <hip/hip_runtime.h>
#include <stdint.h>

// ---- problem constants ----
#define DIMX 1024
#define DIM_INNER 2048
#define BATCH 4
#define SEQ 4096
#define M_TOTAL (BATCH * SEQ)   // 16384
#define N_HG (2 * DIM_INNER)    // 4096
#define NCHUNK 32               // chunks along S
#define CLEN 128                // steps per chunk

typedef unsigned short u16;
typedef __attribute__((ext_vector_type(8))) short short8;   // 8 x bf16 MFMA frag
typedef __attribute__((ext_vector_type(4))) float floatx4;  // MFMA acc
typedef __attribute__((ext_vector_type(2))) unsigned int u32x2;
typedef __attribute__((ext_vector_type(4))) unsigned int u32x4;

// ---- bf16 helpers (bit-level, RNE) ----
__device__ __forceinline__ float bflo(uint32_t u) { return __uint_as_float(u << 16); }
__device__ __forceinline__ float bfhi(uint32_t u) { return __uint_as_float(u & 0xffff0000u); }
__device__ __forceinline__ uint32_t f2bf_bits(float f) {
    uint32_t u = __float_as_uint(f);
    return (u + 0x7fffu + ((u >> 16) & 1u)) >> 16;  // round-to-nearest-even
}

#define GCAST(p) (const __attribute__((address_space(1))) uint32_t*)(const void*)(p)
#define LCAST(p) (__attribute__((address_space(3))) uint32_t*)(void*)(p)
// raw barrier + IR-level fence (plain LDS loads may not cross)
#define BAR()                                          \
    do {                                               \
        __builtin_amdgcn_s_barrier();                  \
        asm volatile("" ::: "memory");                 \
    } while (0)
// drain this wave's ds_reads before the phase's MFMA + pin scheduling (rule #18)
#define LGKM0()                                                  \
    do {                                                         \
        asm volatile("s_waitcnt lgkmcnt(0)" ::: "memory");       \
        __builtin_amdgcn_sched_barrier(0);                       \
    } while (0)
#define VMCNT_(n) asm volatile("s_waitcnt vmcnt(" #n ")" ::: "memory")
#define VMCNT(n) VMCNT_(n)

// ============================================================
// prep kernel: fuses x-cast + Whg transpose + Wout transpose. (unchanged)
// ============================================================
__global__ __launch_bounds__(256) void prep(const float* __restrict__ x,
                                            const float* __restrict__ Whg,
                                            const float* __restrict__ Wout,
                                            u16* __restrict__ xb,
                                            u16* __restrict__ whgt,
                                            u16* __restrict__ woutt) {
    __shared__ float tile[64][65];
    const int bid = blockIdx.x;
    const int tid = threadIdx.x;
    if (bid < 2048) {
        const int n4 = M_TOTAL * DIMX / 4;
        const float4* in4 = (const float4*)x;
        ushort4* out4 = (ushort4*)xb;
        for (int i = bid * 256 + tid; i < n4; i += 2048 * 256) {
            float4 v = in4[i];
            ushort4 o;
            o.x = (u16)f2bf_bits(v.x);
            o.y = (u16)f2bf_bits(v.y);
            o.z = (u16)f2bf_bits(v.z);
            o.w = (u16)f2bf_bits(v.w);
            out4[i] = o;
        }
        return;
    }
    const float* in;
    u16* out;
    int R, C, tb;
    if (bid < 3072) {
        in = Whg; out = whgt; R = DIMX; C = N_HG; tb = bid - 2048;
    } else {
        in = Wout; out = woutt; R = DIM_INNER; C = DIMX; tb = bid - 3072;
    }
    const int tilesx = C / 64;
    const int c0 = (tb % tilesx) * 64, r0 = (tb / tilesx) * 64;
    const int tx = tid & 63, ty = tid >> 6;  // 64 x 4
#pragma unroll
    for (int i = ty; i < 64; i += 4)
        tile[i][tx] = in[(size_t)(r0 + i) * C + c0 + tx];
    __syncthreads();
#pragma unroll
    for (int i = ty; i < 64; i += 4)
        out[(size_t)(c0 + i) * R + r0 + tx] = (u16)f2bf_bits(tile[tx][i]);
}

// ============================================================
// GEMM1 fused (R17 = R13 K-loop + widened av store).
// 8-phase 256-wide template (T2+T3+T4+T5) + XCD remap (T1).
// Epilogue now: fill avl (LDS) only, then repack-store av as dwordx4
// (16 insts/thread, 1KB/wave-inst vs 64 scattered dword = 256B/inst)
// -> 4x fewer store insts, shorter per-generation store drain.
// grid 1024 blocks (1D).
// ============================================================
__global__ __launch_bounds__(512, 2) void gemm1_k(const u16* __restrict__ A,
                                                  const u16* __restrict__ Bt,
                                                  uint32_t* __restrict__ av,
                                                  float2* __restrict__ sumAV) {
    __shared__ alignas(16) u16 smem16[65536];  // 128 KB
    const int tid = threadIdx.x;
    const int lane = tid & 63;
    const int w = tid >> 6;
    const int wr = w >> 2;
    const int wc = w & 3;
    // T1 XCD-aware bijective remap (1024 blocks, 8 XCDs)
    const int wgid = blockIdx.x;
    const int xcd = wgid & 7;
    const int idx = wgid >> 3;          // 0..127
    const int xt = idx & 15;            // column tile 0..15
    const int yt = (idx >> 4) * 8 + xcd; // row tile 0..63, yt%8 == xcd
    const size_t m0 = (size_t)yt * 256;
    const int n0 = xt * 128;
#define X1 0
#define Y1 32768

    floatx4 acch[8][2], accg[8][2];
#pragma unroll
    for (int i = 0; i < 8; ++i)
#pragma unroll
        for (int j = 0; j < 2; ++j) {
            acch[i][j] = (floatx4){0.f, 0.f, 0.f, 0.f};
            accg[i][j] = (floatx4){0.f, 0.f, 0.f, 0.f};
        }

    // fragment addressing (u16 indices); row stride 64 u16, slot = 8 u16 (16B)
    const int fr = lane & 15;
    const int kb = lane >> 4;
    const int sw0 = kb ^ (fr & 7);                       // swizzled slot, kstep 0
    const int a0 = (wr * 128 + fr) * 64 + sw0 * 8;       // kstep1 = a0 ^ 32
    const int a1 = a0 ^ 32;
    const int b0 = 16384 + (wc * 32 + fr) * 64 + sw0 * 8;
    const int b1 = b0 ^ 32;

    // staging: lane covers (row = 8w + lane>>3, slot' = lane&7); global slot
    // = slot' ^ (row&7) = (lane&7)^(lane>>3). LDS dest stays linear.
    const int sr = lane >> 3;
    const int sswz = (lane & 7) ^ sr;
    const u16* pA = A + (m0 + w * 8 + sr) * DIMX + sswz * 8;
    const u16* pBh = Bt + ((size_t)(n0 + w * 8 + sr)) * DIMX + sswz * 8;
    const u16* pBg = pBh + (size_t)DIM_INNER * DIMX;

#define ST1A(bufb, kt, h, l)                                                        \
    __builtin_amdgcn_global_load_lds(                                               \
        GCAST(pA + (size_t)((h) * 128 + (l) * 64) * DIMX + (kt) * 64),              \
        LCAST(smem16 + (bufb) + (h) * 8192 + (l) * 4096 + w * 512), 16, 0, 0)
#define ST1H(bufb, kt, l)                                                           \
    __builtin_amdgcn_global_load_lds(                                               \
        GCAST(pBh + (size_t)((l) * 64) * DIMX + (kt) * 64),                         \
        LCAST(smem16 + (bufb) + 16384 + (l) * 4096 + w * 512), 16, 0, 0)
#define ST1G(bufb, kt, l)                                                           \
    __builtin_amdgcn_global_load_lds(                                               \
        GCAST(pBg + (size_t)((l) * 64) * DIMX + (kt) * 64),                         \
        LCAST(smem16 + (bufb) + 24576 + (l) * 4096 + w * 512), 16, 0, 0)

#define LDS8(idx) (*(const short8*)(smem16 + (idx)))
    short8 af[2][4], bh[2][2], bg[2][2];
#define RDA1(bufb, mh)                                                  \
    do {                                                                \
        _Pragma("unroll") for (int i_ = 0; i_ < 4; ++i_) {              \
            af[0][i_] = LDS8((bufb) + a0 + ((mh) * 4 + i_) * 1024);     \
            af[1][i_] = LDS8((bufb) + a1 + ((mh) * 4 + i_) * 1024);     \
        }                                                               \
    } while (0)
#define RDBH1(bufb)                                                     \
    do {                                                                \
        _Pragma("unroll") for (int j_ = 0; j_ < 2; ++j_) {              \
            bh[0][j_] = LDS8((bufb) + b0 + j_ * 1024);                  \
            bh[1][j_] = LDS8((bufb) + b1 + j_ * 1024);                  \
        }                                                               \
    } while (0)
#define RDBG1(bufb)                                                     \
    do {                                                                \
        _Pragma("unroll") for (int j_ = 0; j_ < 2; ++j_) {              \
            bg[0][j_] = LDS8((bufb) + b0 + 8192 + j_ * 1024);           \
            bg[1][j_] = LDS8((bufb) + b1 + 8192 + j_ * 1024);           \
        }                                                               \
    } while (0)
#define MM1(ACC, IB, BF)                                                                     \
    do {                                                                                     \
        __builtin_amdgcn_s_setprio(1);                                                       \
        _Pragma("unroll") for (int i_ = 0; i_ < 4; ++i_)                                     \
            _Pragma("unroll") for (int j_ = 0; j_ < 2; ++j_) {                               \
            ACC[(IB) + i_][j_] = __builtin_amdgcn_mfma_f32_16x16x32_bf16(                    \
                af[0][i_], BF[0][j_], ACC[(IB) + i_][j_], 0, 0, 0);                          \
            ACC[(IB) + i_][j_] = __builtin_amdgcn_mfma_f32_16x16x32_bf16(                    \
                af[1][i_], BF[1][j_], ACC[(IB) + i_][j_], 0, 0, 0);                          \
        }                                                                                    \
        __builtin_amdgcn_s_setprio(0);                                                       \
    } while (0)

#define ITER1(t, FULL, G4, G8)                                                               \
    do {                                                                                     \
        /* ph1: q(mh0,h) of tile t (X) */                                                    \
        RDA1(X1, 0); RDBH1(X1);                                                              \
        ST1A(Y1, (t) + 1, 1, 0); ST1A(Y1, (t) + 1, 1, 1);                                    \
        BAR(); LGKM0(); MM1(acch, 0, bh); BAR();                                             \
        /* ph2: q(mh0,g) */                                                                  \
        RDBG1(X1);                                                                           \
        if (FULL) { ST1H(X1, (t) + 2, 0); ST1H(X1, (t) + 2, 1); }                            \
        BAR(); LGKM0(); MM1(accg, 0, bg); BAR();                                             \
        /* ph3: q(mh1,h) */                                                                  \
        RDA1(X1, 1);                                                                         \
        if (FULL) { ST1G(X1, (t) + 2, 0); ST1G(X1, (t) + 2, 1); }                            \
        BAR(); LGKM0(); MM1(acch, 4, bh); BAR();                                             \
        /* ph4: q(mh1,g); gate */                                                            \
        if (FULL) { ST1A(X1, (t) + 2, 0, 0); ST1A(X1, (t) + 2, 0, 1); }                      \
        VMCNT(G4); BAR(); MM1(accg, 4, bg); BAR();                                           \
        /* ph5: q(mh0,h) of tile t+1 (Y) */                                                  \
        RDA1(Y1, 0); RDBH1(Y1);                                                              \
        if (FULL) { ST1A(X1, (t) + 2, 1, 0); ST1A(X1, (t) + 2, 1, 1); }                      \
        BAR(); LGKM0(); MM1(acch, 0, bh); BAR();                                             \
        /* ph6: q(mh0,g) */                                                                  \
        RDBG1(Y1);                                                                           \
        if (FULL) { ST1H(Y1, (t) + 3, 0); ST1H(Y1, (t) + 3, 1); }                            \
        BAR(); LGKM0(); MM1(accg, 0, bg); BAR();                                             \
        /* ph7: q(mh1,h) */                                                                  \
        RDA1(Y1, 1);                                                                         \
        if (FULL) { ST1G(Y1, (t) + 3, 0); ST1G(Y1, (t) + 3, 1); }                            \
        BAR(); LGKM0(); MM1(acch, 4, bh); BAR();                                             \
        /* ph8: q(mh1,g); gate */                                                            \
        if (FULL) { ST1A(Y1, (t) + 3, 0, 0); ST1A(Y1, (t) + 3, 0, 1); }                      \
        VMCNT(G8); BAR(); MM1(accg, 4, bg); BAR();                                           \
    } while (0)

    // prologue: 7 half-tiles; vmcnt(6) -> tile0's 4 halves landed
    ST1H(X1, 0, 0); ST1H(X1, 0, 1);        // Bh(0)
    ST1G(X1, 0, 0); ST1G(X1, 0, 1);        // Bg(0)
    ST1A(X1, 0, 0, 0); ST1A(X1, 0, 0, 1);  // A0(0)
    ST1A(X1, 0, 1, 0); ST1A(X1, 0, 1, 1);  // A1(0)
    ST1H(Y1, 1, 0); ST1H(Y1, 1, 1);        // Bh(1)
    ST1G(Y1, 1, 0); ST1G(Y1, 1, 1);        // Bg(1)
    ST1A(Y1, 1, 0, 0); ST1A(Y1, 1, 0, 1);  // A0(1)
    VMCNT(6); BAR();
#pragma unroll 1
    for (int it = 0; it < 7; ++it) ITER1(2 * it, 1, 6, 6);
    ITER1(14, 0, 0, 6);  // tiles 14,15; ph1 stages A1(15); ph4 drains all

    __syncthreads();  // staging LDS dead; reuse as avl [256][128] u32 = 128 KB

    uint32_t* avl = (uint32_t*)smem16;
    const int r0row = (lane >> 4) * 4;
#pragma unroll
    for (int i = 0; i < 8; ++i) {
#pragma unroll
        for (int r = 0; r < 4; ++r) {
            const int row = wr * 128 + i * 16 + r0row + r;
#pragma unroll
            for (int j = 0; j < 2; ++j) {
                const int col = wc * 32 + j * 16 + fr;
                float h = acch[i][j][r];
                float g = accg[i][j][r];
                g = fminf(fmaxf(g, -30.f), 30.f);
                float e = __expf(-g);
                float z = 1.f / (1.f + e);
                float a = e * z;                       // 1 - sigmoid(g)
                float v = z * (fmaxf(h, 0.f) + 0.5f);  // sigmoid(g)*(relu(h)+0.5)
                avl[row * 128 + col] = f2bf_bits(a) | (f2bf_bits(v) << 16);
            }
        }
    }
    __syncthreads();

    // wide av store from avl: 16 x (ds_read_b128 + global dwordx4) per thread
#pragma unroll
    for (int s = 0; s < 16; ++s) {
        const int ix = s * 512 + tid;       // 0..8191 16B-chunks
        const int row = ix >> 5;            // 256 rows
        const int slot = ix & 31;           // 32 x 16B per row
        u32x4 val = *(const u32x4*)(avl + row * 128 + slot * 4);
        *(u32x4*)(av + (m0 + row) * 2048 + n0 + slot * 4) = val;
    }

    // in-block chunk-summary scan: block covers 2 chunks of 128 rows
    const int chl = tid >> 8;  // chunk-local 0/1
    const int t2 = tid & 255;
    const int col = t2 & 127;
    const int rlo = (t2 >> 7) * 64;
    float Aa = 1.f, Vv = 0.f;
#pragma unroll 8
    for (int j = 0; j < 64; ++j) {
        uint32_t pk = avl[(chl * 128 + rlo + j) * 128 + col];
        float a = bflo(pk), v = bfhi(pk);
        Vv = fmaf(a, Vv, v);
        Aa *= a;
    }
    __syncthreads();
    if (rlo == 0) {
        avl[chl * 256 + col] = __float_as_uint(Aa);
        avl[chl * 256 + 128 + col] = __float_as_uint(Vv);
    }
    __syncthreads();
    if (rlo != 0) {
        float Al = __uint_as_float(avl[chl * 256 + col]);
        float Vl = __uint_as_float(avl[chl * 256 + 128 + col]);
        float At = Al * Aa;
        float Vt = fmaf(Aa, Vl, Vv);
        const int chunk = (int)(m0 >> 7) + chl;  // global chunk id = b*32+ch
        sumAV[(size_t)chunk * 2048 + n0 + col] = (float2){At, Vt};
    }
#undef ST1A
#undef ST1H
#undef ST1G
#undef RDA1
#undef RDBH1
#undef RDBG1
#undef MM1
#undef ITER1
}

// ============================================================
// GEMM2 (unchanged R13/R16: 8-phase 256x256, plain C stores).
// grid (4, 64) = 256 blocks.
// ============================================================
__global__ __launch_bounds__(512, 2) void gemm2_k(const u16* __restrict__ A,
                                                  const u16* __restrict__ Bt,
                                                  float* __restrict__ C) {
    const int N = DIMX, K = DIM_INNER;
    __shared__ alignas(16) u16 smem16[65536];  // 128 KB
    const int tid = threadIdx.x;
    const int lane = tid & 63;
    const int w = tid >> 6;
    const int wr = w >> 2;
    const int wc = w & 3;
    const size_t m0 = (size_t)blockIdx.y * 256;
    const size_t n0 = (size_t)blockIdx.x * 256;

    floatx4 acc[8][4];
#pragma unroll
    for (int i = 0; i < 8; ++i)
#pragma unroll
        for (int j = 0; j < 4; ++j) acc[i][j] = (floatx4){0.f, 0.f, 0.f, 0.f};

    const int fr = lane & 15;
    const int kb = lane >> 4;
    const int sw0 = kb ^ (fr & 7);
    const int a0 = (wr * 128 + fr) * 64 + sw0 * 8;
    const int a1 = a0 ^ 32;
    const int b0 = 16384 + (wc * 64 + fr) * 64 + sw0 * 8;
    const int b1 = b0 ^ 32;

    const int sr = lane >> 3;
    const int sswz = (lane & 7) ^ sr;
    const u16* pA = A + (m0 + w * 8 + sr) * K + sswz * 8;
    const u16* pB = Bt + (n0 + w * 8 + sr) * K + sswz * 8;

#define ST2A(bufb, kt, h, l)                                                        \
    __builtin_amdgcn_global_load_lds(                                               \
        GCAST(pA + (size_t)((h) * 128 + (l) * 64) * K + (kt) * 64),                 \
        LCAST(smem16 + (bufb) + (h) * 8192 + (l) * 4096 + w * 512), 16, 0, 0)
#define ST2B(bufb, kt, h, l)                                                        \
    __builtin_amdgcn_global_load_lds(                                               \
        GCAST(pB + (size_t)((h) * 128 + (l) * 64) * K + (kt) * 64),                 \
        LCAST(smem16 + (bufb) + 16384 + (h) * 8192 + (l) * 4096 + w * 512), 16, 0, 0)

    short8 af[2][4], ba[2][2], bb[2][2];
#define RDA2(bufb, mh)                                                  \
    do {                                                                \
        _Pragma("unroll") for (int i_ = 0; i_ < 4; ++i_) {              \
            af[0][i_] = LDS8((bufb) + a0 + ((mh) * 4 + i_) * 1024);     \
            af[1][i_] = LDS8((bufb) + a1 + ((mh) * 4 + i_) * 1024);     \
        }                                                               \
    } while (0)
#define RDB2(bufb, BF, nh)                                                  \
    do {                                                                    \
        _Pragma("unroll") for (int j_ = 0; j_ < 2; ++j_) {                  \
            BF[0][j_] = LDS8((bufb) + b0 + ((nh) * 2 + j_) * 1024);         \
            BF[1][j_] = LDS8((bufb) + b1 + ((nh) * 2 + j_) * 1024);         \
        }                                                                   \
    } while (0)
#define MM2(IB, JB, BF)                                                                      \
    do {                                                                                     \
        __builtin_amdgcn_s_setprio(1);                                                       \
        _Pragma("unroll") for (int i_ = 0; i_ < 4; ++i_)                                     \
            _Pragma("unroll") for (int j_ = 0; j_ < 2; ++j_) {                               \
            acc[(IB) + i_][(JB) + j_] = __builtin_amdgcn_mfma_f32_16x16x32_bf16(             \
                af[0][i_], BF[0][j_], acc[(IB) + i_][(JB) + j_], 0, 0, 0);                   \
            acc[(IB) + i_][(JB) + j_] = __builtin_amdgcn_mfma_f32_16x16x32_bf16(             \
                af[1][i_], BF[1][j_], acc[(IB) + i_][(JB) + j_], 0, 0, 0);                   \
        }                                                                                    \
        __builtin_amdgcn_s_setprio(0);                                                       \
    } while (0)

#define ITER2(t, FULL, G4, G8)                                                               \
    do {                                                                                     \
        /* ph1 */ RDA2(X1, 0); RDB2(X1, ba, 0);                                              \
        ST2A(Y1, (t) + 1, 0, 0); ST2A(Y1, (t) + 1, 0, 1);                                    \
        BAR(); LGKM0(); MM2(0, 0, ba); BAR();                                                \
        /* ph2 */ RDB2(X1, bb, 1);                                                           \
        ST2A(Y1, (t) + 1, 1, 0); ST2A(Y1, (t) + 1, 1, 1);                                    \
        BAR(); LGKM0(); MM2(0, 2, bb); BAR();                                                \
        /* ph3 */ RDA2(X1, 1);                                                               \
        if (FULL) { ST2B(X1, (t) + 2, 0, 0); ST2B(X1, (t) + 2, 0, 1); }                      \
        BAR(); LGKM0(); MM2(4, 0, ba); BAR();                                                \
        /* ph4 */                                                                            \
        if (FULL) { ST2B(X1, (t) + 2, 1, 0); ST2B(X1, (t) + 2, 1, 1); }                      \
        VMCNT(G4); BAR(); MM2(4, 2, bb); BAR();                                              \
        /* ph5 */ RDA2(Y1, 0); RDB2(Y1, ba, 0);                                              \
        if (FULL) { ST2A(X1, (t) + 2, 0, 0); ST2A(X1, (t) + 2, 0, 1); }                      \
        BAR(); LGKM0(); MM2(0, 0, ba); BAR();                                                \
        /* ph6 */ RDB2(Y1, bb, 1);                                                           \
        if (FULL) { ST2A(X1, (t) + 2, 1, 0); ST2A(X1, (t) + 2, 1, 1); }                      \
        BAR(); LGKM0(); MM2(0, 2, bb); BAR();                                                \
        /* ph7 */ RDA2(Y1, 1);                                                               \
        if (FULL) { ST2B(Y1, (t) + 3, 0, 0); ST2B(Y1, (t) + 3, 0, 1); }                      \
        BAR(); LGKM0(); MM2(4, 0, ba); BAR();                                                \
        /* ph8 */                                                                            \
        if (FULL) { ST2B(Y1, (t) + 3, 1, 0); ST2B(Y1, (t) + 3, 1, 1); }                      \
        VMCNT(G8); BAR(); MM2(4, 2, bb); BAR();                                              \
    } while (0)

    // prologue: 6 half-tiles; vmcnt(4) -> tile0's 4 halves landed
    ST2B(X1, 0, 0, 0); ST2B(X1, 0, 0, 1);  // B0(0)
    ST2B(X1, 0, 1, 0); ST2B(X1, 0, 1, 1);  // B1(0)
    ST2A(X1, 0, 0, 0); ST2A(X1, 0, 0, 1);  // A0(0)
    ST2A(X1, 0, 1, 0); ST2A(X1, 0, 1, 1);  // A1(0)
    ST2B(Y1, 1, 0, 0); ST2B(Y1, 1, 0, 1);  // B0(1)
    ST2B(Y1, 1, 1, 0); ST2B(Y1, 1, 1, 1);  // B1(1)
    VMCNT(4); BAR();
#pragma unroll 1
    for (int it = 0; it < 15; ++it) ITER2(2 * it, 1, 4, 4);
    ITER2(30, 0, 0, 4);  // tiles 30,31; ph1/ph2 stage A(31); ph4 drains all

    const int r0row = (lane >> 4) * 4;
#pragma unroll
    for (int i = 0; i < 8; ++i)
#pragma unroll
        for (int r = 0; r < 4; ++r) {
            size_t row = m0 + wr * 128 + i * 16 + r0row + r;
#pragma unroll
            for (int j = 0; j < 4; ++j) {
                size_t col = n0 + wc * 64 + j * 16 + fr;
                C[row * N + col] = acc[i][j][r];
            }
        }
#undef ST2A
#undef ST2B
#undef RDA2
#undef RDB2
#undef MM2
#undef ITER2
}

// ============================================================
// Phase B restored (R17): carry scan as its own tiny kernel (~3 us).
// The R14 merge made late-chunk scan_apply blocks pay up to 31 serial
// dependent-latency loads before streaming — a tail pessimization.
// ============================================================
__global__ __launch_bounds__(64) void scan_carry(const float2* __restrict__ sumAV,
                                                 float* __restrict__ carry) {
    const int g = blockIdx.x * 64 + threadIdx.x;  // 0..8191
    const int b = g >> 11, c = g & 2047;
    float h = 0.f;
#pragma unroll 8
    for (int ch = 0; ch < NCHUNK; ++ch) {
        float2 s = sumAV[(size_t)(b * NCHUNK + ch) * 2048 + c];
        carry[(size_t)(b * NCHUNK + ch) * 2048 + c] = h;
        h = fmaf(s.x, h, s.y);
    }
}

// ============================================================
// Phase C (R17): replay with 16-deep row prefetch (128 B/thread in
// flight -> BW-bound, not latency-bound); carry read directly.
// grid (4, NCHUNK, BATCH) x 256; thread -> 2 channels.
// ============================================================
__global__ __launch_bounds__(256) void scan_apply(const uint32_t* __restrict__ av,
                                                  const float* __restrict__ carry,
                                                  uint32_t* __restrict__ hbuf) {
    const int b = blockIdx.z, ch = blockIdx.y;
    const int c2 = blockIdx.x * 256 + threadIdx.x;  // channel-pair 0..1023
    const size_t rowbase = (size_t)b * SEQ + (size_t)ch * CLEN;
    const uint32_t* p = av + rowbase * 2048 + c2 * 2;
    uint32_t* q = hbuf + rowbase * 1024 + c2;
    const float2 cin = ((const float2*)carry)[(size_t)(b * NCHUNK + ch) * 1024 + c2];
    float h0 = cin.x, h1 = cin.y;

    u32x2 buf[16];
#pragma unroll
    for (int t = 0; t < 16; ++t) buf[t] = *(const u32x2*)(p + (size_t)t * 2048);

    for (int j0 = 0; j0 < CLEN; j0 += 16) {
        u32x2 nxt[16];
        if (j0 + 16 < CLEN) {
#pragma unroll
            for (int t = 0; t < 16; ++t)
                nxt[t] = *(const u32x2*)(p + (size_t)(j0 + 16 + t) * 2048);
        }
#pragma unroll
        for (int t = 0; t < 16; ++t) {
            float a0 = bflo(buf[t].x), v0 = bfhi(buf[t].x);
            float a1 = bflo(buf[t].y), v1 = bfhi(buf[t].y);
            h0 = fmaf(a0, h0, v0);
            h1 = fmaf(a1, h1, v1);
            q[(size_t)(j0 + t) * 1024] = f2bf_bits(h0) | (f2bf_bits(h1) << 16);
        }
#pragma unroll
        for (int t = 0; t < 16; ++t) buf[t] = nxt[t];
    }
}

// ============================================================
extern "C" void kernel_launch(void* const* d_in, const int* in_sizes, int n_in,
                              void* d_out, int out_size, void* d_ws, size_t ws_size,
                              hipStream_t stream) {
    const float* x = (const float*)d_in[0];     // [16384,1024]
    const float* Whg = (const float*)d_in[1];   // [1024,4096]
    const float* Wout = (const float*)d_in[2];  // [2048,1024]

    char* ws = (char*)d_ws;
    size_t off = 0;
    u16* xb = (u16*)(ws + off);        off += (size_t)M_TOTAL * DIMX * 2;          // 33.6 MB
    u16* whgt = (u16*)(ws + off);      off += (size_t)N_HG * DIMX * 2;             // 8.4 MB
    u16* woutt = (u16*)(ws + off);     off += (size_t)DIMX * DIM_INNER * 2;        // 4.2 MB
    uint32_t* av = (uint32_t*)(ws + off); off += (size_t)M_TOTAL * DIM_INNER * 4;  // 134.2 MB
    uint32_t* hbuf = (uint32_t*)(ws + off); off += (size_t)M_TOTAL * DIM_INNER * 2; // 67.1 MB
    float2* sumAV = (float2*)(ws + off); off += (size_t)BATCH * NCHUNK * DIM_INNER * 8; // 2.1 MB
    // carry (1 MB) aliases whgt: whgt dead after gemm1_k (stream-ordered).
    float* carry = (float*)whgt;

    // 1. fused prep
    prep<<<2048 + 1024 + 512, 256, 0, stream>>>(x, Whg, Wout, xb, whgt, woutt);

    // 2. GEMM1 fused (8-phase + XCD remap + wide av store)
    gemm1_k<<<1024, 512, 0, stream>>>(xb, whgt, av, sumAV);

    // 3. carry scan (tiny) + replay (16-deep prefetch)
    scan_carry<<<128, 64, 0, stream>>>(sumAV, carry);
    scan_apply<<<dim3(4, NCHUNK, BATCH), 256, 0, stream>>>(av, carry, hbuf);

    // 4. GEMM2 (8-phase): out = h @ Wout (fp32 out), 256x256 tiles
    gemm2_k<<<dim3(DIMX / 256, M_TOTAL / 256), 512, 0, stream>>>((const u16*)hbuf, woutt, (float*)d_out);
}